// Round 4
// baseline (184.424 us; speedup 1.0000x reference)
//
#include <hip/hip_runtime.h>
#include <cstddef>
#include <cstdint>

#define SEQ 2048
#define DM 1024
#define NH 16
#define HD 64

typedef _Float16 f16;
typedef __attribute__((ext_vector_type(8))) _Float16 f16x8;
typedef __attribute__((ext_vector_type(4))) _Float16 f16x4;
typedef __attribute__((ext_vector_type(2))) _Float16 f16x2;
typedef __attribute__((ext_vector_type(4))) float f32x4;

// one launch: cast x (1M float4) + 4 weights (256K float4 each) into the
// contiguous 16 MB f16 region [xb | Wq | Wk | Wv | Wo]
__global__ __launch_bounds__(256) void cast_all(const float* __restrict__ x,
                                                const float* __restrict__ Wq,
                                                const float* __restrict__ Wk,
                                                const float* __restrict__ Wv,
                                                const float* __restrict__ Wo,
                                                f16* __restrict__ dst) {
  const int i = blockIdx.x * 256 + threadIdx.x;  // float4 index, 2M total
  const float* src;
  int off;
  if (i < 1048576) {
    src = x; off = i;
  } else {
    const int j = i - 1048576;
    const int wsel = j >> 18;
    src = (wsel == 0) ? Wq : (wsel == 1) ? Wk : (wsel == 2) ? Wv : Wo;
    off = j & 262143;
  }
  const float4 v = ((const float4*)src)[off];
  f16x4 o = {(f16)v.x, (f16)v.y, (f16)v.z, (f16)v.w};
  ((f16x4*)dst)[i] = o;
}

__device__ __forceinline__ void gload16(const void* g, void* lds) {
  __builtin_amdgcn_global_load_lds((const __attribute__((address_space(1))) void*)g,
                                   (__attribute__((address_space(3))) void*)lds,
                                   16, 0, 0);
}

// ---------------------------------------------------------------------------
// f16 GEMM mainloop, BK=64 (16 K-steps, half the barriers of BK=32).
// LDS tiles are XOR-swizzled (T2, st-16B granule): dest col-group sg holds
// source col-group sg^(row&7). gload_lds writes linearly (wave base + lane*16),
// so the swizzle is applied on the per-lane GLOBAL source address (m173) and
// inverted on the ds_read side. Bank math: frag reads land 64x16B over all 32
// banks at 32B/bank = the b128 minimum -> conflict-free.
// ---------------------------------------------------------------------------
__device__ __forceinline__ void gemm_tile(const f16* __restrict__ A,
                                          const f16* __restrict__ B,
                                          f16* As, f16* Bs,
                                          int K, f32x4 acc[4][4]) {
  const int t = threadIdx.x;
  const int lane = t & 63;
  const int w = t >> 6;
  const int wm = (w & 1) << 6, wn = (w >> 1) << 6;
  const int srow = lane >> 3, sg = lane & 7;
  const int fr = lane & 15, q = lane >> 4;
  const int scol = (sg ^ srow) << 3;  // swizzled source col (f16)
  for (int k0 = 0; k0 < K; k0 += 64) {
    __syncthreads();
#pragma unroll
    for (int c = 0; c < 4; ++c) {
      const int row = (w << 5) + (c << 3) + srow;  // row&7 == srow
      gload16(A + (size_t)row * K + k0 + scol, As + (w << 11) + (c << 9));
      gload16(B + (size_t)row * K + k0 + scol, Bs + (w << 11) + (c << 9));
    }
    __syncthreads();
    f16x8 af[4][2], bf[4][2];
#pragma unroll
    for (int i = 0; i < 4; ++i) {
      const int row = wm + (i << 4) + fr;
#pragma unroll
      for (int kh = 0; kh < 2; ++kh)
        af[i][kh] = *(const f16x8*)(As + row * 64 +
                                    ((((kh << 2) | q) ^ (row & 7)) << 3));
    }
#pragma unroll
    for (int j = 0; j < 4; ++j) {
      const int row = wn + (j << 4) + fr;
#pragma unroll
      for (int kh = 0; kh < 2; ++kh)
        bf[j][kh] = *(const f16x8*)(Bs + row * 64 +
                                    ((((kh << 2) | q) ^ (row & 7)) << 3));
    }
#pragma unroll
    for (int kh = 0; kh < 2; ++kh)
#pragma unroll
      for (int i = 0; i < 4; ++i)
#pragma unroll
        for (int j = 0; j < 4; ++j)
          acc[i][j] = __builtin_amdgcn_mfma_f32_16x16x32_f16(af[i][kh], bf[j][kh],
                                                             acc[i][j], 0, 0, 0);
  }
}

// Fused QKV projection. Q pre-scaled by log2(e)/sqrt(d_model).
// V stored in gload_lds-linear frag layout; per 64-key tile kt (4096 elems):
//   flat = bh*131072 + kt*4096 + kc*1024 + quad*256 + d*4 + e
//   holding V[d][s = kt*64 + kc*16 + quad*4 + e]   (d = head dim 0..63)
// The 4KB tile is a byte-linear LDS image for attn; the epilogue's f16x4
// (4 consecutive s, fixed d) is contiguous -> fully coalesced stores.
#define QSCALE 0.04508422003f /* 1.4426950409/32 */
__global__ __launch_bounds__(256) void gemm_qkv(
    const f16* __restrict__ xb, const f16* __restrict__ Wqb,
    const f16* __restrict__ Wkb, const f16* __restrict__ Wvb,
    f16* __restrict__ Qb, f16* __restrict__ Kb, f16* __restrict__ Vtg) {
  __shared__ f16 smem[16384];
  f16* As = smem;
  f16* Bs = smem + 8192;
  const int which = blockIdx.x >> 3;
  const int bn = (blockIdx.x & 7) << 7;
  const int bm = blockIdx.y << 7;
  const f16* B = (which == 0) ? Wqb : (which == 1) ? Wkb : Wvb;
  f32x4 acc[4][4] = {};
  gemm_tile(xb + (size_t)bm * DM, B + (size_t)bn * DM, As, Bs, DM, acc);
  const int lane = threadIdx.x & 63, w = threadIdx.x >> 6;
  const int wm = (w & 1) << 6, wn = (w >> 1) << 6;
  const int col = lane & 15, q = lane >> 4;
  if (which < 2) {
    f16* C = (which == 0) ? Qb : Kb;
    const float sc = (which == 0) ? QSCALE : 1.0f;
#pragma unroll
    for (int i = 0; i < 4; ++i) {
      const int m = bm + wm + (i << 4) + (q << 2);
#pragma unroll
      for (int j = 0; j < 4; ++j) {
        const int n = bn + wn + (j << 4) + col;
#pragma unroll
        for (int r = 0; r < 4; ++r)
          C[(size_t)(m + r) * DM + n] = (f16)(acc[i][j][r] * sc);
      }
    }
  } else {
    // LDS transpose T[nl][m] (swizzled chunks), then frag-layout global stores.
    __syncthreads();
#pragma unroll
    for (int i = 0; i < 4; ++i) {
      const int m0 = wm + (i << 4) + (q << 2);
      const int cm = m0 >> 3, sub = (m0 >> 2) & 1;
#pragma unroll
      for (int j = 0; j < 4; ++j) {
        const int nl = wn + (j << 4) + col;
        f16x4 o = {(f16)acc[i][j][0], (f16)acc[i][j][1],
                   (f16)acc[i][j][2], (f16)acc[i][j][3]};
        *(f16x4*)(smem + nl * 128 +
                  ((cm ^ (nl & 15) ^ ((nl >> 4) & 3)) << 3) + (sub << 2)) = o;
      }
    }
    __syncthreads();
    const int b = bm >> 11, sb = bm & 2047;
    const int d = threadIdx.x & 63;
#pragma unroll
    for (int step = 0; step < 16; ++step) {
      const int idx = (threadIdx.x >> 6) + (step << 2);  // 0..63
      const int hh = idx >> 5, s4 = idx & 31;
      const int nl = (hh << 6) + d;
      const int cm = s4 >> 1, sub = s4 & 1;
      const f16x4 v = *(const f16x4*)(smem + nl * 128 +
                                      ((cm ^ (nl & 15) ^ ((nl >> 4) & 3)) << 3) +
                                      (sub << 2));
      const int bh = (b << 4) + (bn >> 6) + hh;
      const int sg = sb + (s4 << 2);
      // flat = bh*131072 + kt*4096 + kc*1024 + quad*256 + d*4 (+ e from f16x4)
      const size_t flat = ((size_t)bh << 17) + ((size_t)(sg >> 6) << 12) +
                          (((size_t)(s4 >> 2) & 3) << 10) +
                          (((size_t)s4 & 3) << 8) + ((size_t)d << 2);
      *(f16x4*)(Vtg + flat) = v;
    }
  }
}

// Output projection: 128x64 tiles, BK=64, grid (16,32)=512 blocks (2/CU).
__global__ __launch_bounds__(256) void gemm_out(const f16* __restrict__ Ab,
                                                const f16* __restrict__ Wob,
                                                float* __restrict__ out) {
  __shared__ f16 As[128 * 64];
  __shared__ f16 Bs[64 * 64];
  const int bn = blockIdx.x << 6, bm = blockIdx.y << 7;
  const int t = threadIdx.x, lane = t & 63, w = t >> 6;
  const int srow = lane >> 3, sg = lane & 7;
  const int fr = lane & 15, q = lane >> 4;
  const int scol = (sg ^ srow) << 3;
  const f16* A = Ab + (size_t)bm * DM;
  const f16* B = Wob + (size_t)bn * DM;
  const int wm = w << 5;
  f32x4 acc[2][4] = {};
  for (int k0 = 0; k0 < DM; k0 += 64) {
    __syncthreads();
#pragma unroll
    for (int c = 0; c < 4; ++c) {
      const int row = (w << 5) + (c << 3) + srow;
      gload16(A + (size_t)row * DM + k0 + scol, As + (w << 11) + (c << 9));
    }
#pragma unroll
    for (int c = 0; c < 2; ++c) {
      const int row = (w << 4) + (c << 3) + srow;
      gload16(B + (size_t)row * DM + k0 + scol, Bs + (w << 10) + (c << 9));
    }
    __syncthreads();
    f16x8 af[2][2], bf[4][2];
#pragma unroll
    for (int i = 0; i < 2; ++i) {
      const int row = wm + (i << 4) + fr;
#pragma unroll
      for (int kh = 0; kh < 2; ++kh)
        af[i][kh] = *(const f16x8*)(As + row * 64 +
                                    ((((kh << 2) | q) ^ (row & 7)) << 3));
    }
#pragma unroll
    for (int j = 0; j < 4; ++j) {
      const int row = (j << 4) + fr;
#pragma unroll
      for (int kh = 0; kh < 2; ++kh)
        bf[j][kh] = *(const f16x8*)(Bs + row * 64 +
                                    ((((kh << 2) | q) ^ (row & 7)) << 3));
    }
#pragma unroll
    for (int kh = 0; kh < 2; ++kh)
#pragma unroll
      for (int i = 0; i < 2; ++i)
#pragma unroll
        for (int j = 0; j < 4; ++j)
          acc[i][j] = __builtin_amdgcn_mfma_f32_16x16x32_f16(af[i][kh], bf[j][kh],
                                                             acc[i][j], 0, 0, 0);
  }
  const int col = lane & 15;
#pragma unroll
  for (int i = 0; i < 2; ++i) {
    const int m = bm + wm + (i << 4) + (q << 2);
#pragma unroll
    for (int j = 0; j < 4; ++j) {
      const int n = bn + (j << 4) + col;
#pragma unroll
      for (int r = 0; r < 4; ++r)
        out[(size_t)(m + r) * DM + n] = acc[i][j][r];
    }
  }
}

// ---------------------------------------------------------------------------
// MFMA flash attention R12 (resubmit): occupancy 2 -> 4 blocks/CU.
// Grid 1024 (was 512): each block handles 64 q rows (1 q-tile of 16 per wave,
// was 2). Per-SIMD MFMA work per body unchanged (4 waves x 24 = 2 x 48), but
// barriers now sync 4 independent blocks per CU -> one block's barrier drain
// overlaps another's compute. LDS 32 KB/block x 4 = 128 KB <= 160.
// K/V staging identical (per-block, q-independent).
// ---------------------------------------------------------------------------
__global__ __launch_bounds__(256, 4) void attn_mfma(const f16* __restrict__ Qb,
                                                    const f16* __restrict__ Kb,
                                                    const f16* __restrict__ Vtg,
                                                    f16* __restrict__ Ctx) {
  __shared__ f16 smem[16384];  // 32 KB: K0 | K1 | V0 | V1 (8 KB each)
  const int t = threadIdx.x, lane = t & 63, w = t >> 6;
  const int fr = lane & 15, quad = lane >> 4;
  const int i = blockIdx.x;
  const int j = i >> 3;                      // 0..127
  const int bh = ((i & 7) << 2) + (j >> 5);  // same-bh blocks -> same XCD
  const int qt32 = j & 31;
  const int b = bh >> 4, h = bh & 15;

  const size_t qrow0 = (size_t)b * SEQ + qt32 * 64 + w * 16;

  // Q^T B-frags, loop-invariant (one 16-row q-tile per wave)
  f16x8 Qf[2];
#pragma unroll
  for (int hf = 0; hf < 2; ++hf)
    Qf[hf] = *(const f16x8*)(Qb + (qrow0 + fr) * DM + h * HD +
                             hf * 32 + (quad << 3));

  // K gload_lds: LDS slot s (=lane) must hold global (krow = s>>2,
  // kkc = ((s&3) - (s>>3)) & 3)  — the inverse of cwr(krow,kkc).
  const int krow = lane >> 2;
  const int kkc = ((lane & 3) - (lane >> 3)) & 3;
  const f16* Kg = Kb + ((size_t)b * SEQ + 16 * w + krow) * DM + h * HD + (kkc << 3);
  // V gload_lds: linear copy; wave w stages slots w*128 + c*64 + lane.
  const f16* Vg = Vtg + ((size_t)bh << 17) + (((w << 7) + lane) << 3);

  const int crd = ((fr >> 1) << 3) | ((fr & 1) << 2) | (((fr >> 1) + quad) & 3);

  f16* K0 = smem;
  f16* K1 = smem + 4096;
  f16* V0 = smem + 8192;
  f16* V1 = smem + 12288;

  auto stage = [&](int kt, f16* Kimg, f16* Vimg) {
#pragma unroll
    for (int hf = 0; hf < 2; ++hf)
      gload16(Kg + (size_t)kt * 64 * DM + hf * 32,
              Kimg + (hf << 11) + (w << 9));
#pragma unroll
    for (int c = 0; c < 2; ++c)
      gload16(Vg + kt * 4096 + (c << 9), Vimg + (w << 10) + (c << 9));
  };

  f32x4 acc[4] = {};
  float lacc = 0.f;

  stage(0, K0, V0);

  auto body = [&](int kt, f16* KR, f16* VR, f16* KW, f16* VW) {
    __syncthreads();  // publishes KR/VR (tile kt); drains last body's prefetch
    if (kt < 31) stage(kt + 1, KW, VW);

    f16x8 Kf[4][2];
#pragma unroll
    for (int mt = 0; mt < 4; ++mt)
#pragma unroll
      for (int hf = 0; hf < 2; ++hf)
        Kf[mt][hf] = *(const f16x8*)(KR + (crd << 3) + (hf << 11) + (mt << 9));
    f16x4 Vf[4][4];
#pragma unroll
    for (int dt = 0; dt < 4; ++dt)
#pragma unroll
      for (int kc = 0; kc < 4; ++kc)
        Vf[dt][kc] = *(const f16x4*)(VR + (kc << 10) + (quad << 8) +
                                     (((dt << 4) | fr) << 2));

    f32x4 z[4] = {};
#pragma unroll
    for (int hf = 0; hf < 2; ++hf)
#pragma unroll
      for (int mt = 0; mt < 4; ++mt)
        z[mt] = __builtin_amdgcn_mfma_f32_16x16x32_f16(Kf[mt][hf], Qf[hf],
                                                       z[mt], 0, 0, 0);

    f16x4 pf[4];
#pragma unroll
    for (int mt = 0; mt < 4; ++mt) {
      const float p0 = __builtin_amdgcn_exp2f(z[mt][0]);
      const float p1 = __builtin_amdgcn_exp2f(z[mt][1]);
      const float p2 = __builtin_amdgcn_exp2f(z[mt][2]);
      const float p3 = __builtin_amdgcn_exp2f(z[mt][3]);
      lacc += (p0 + p1) + (p2 + p3);
      const f16x2 lo = __builtin_bit_cast(f16x2, __builtin_amdgcn_cvt_pkrtz(p0, p1));
      const f16x2 hi = __builtin_bit_cast(f16x2, __builtin_amdgcn_cvt_pkrtz(p2, p3));
      f16x4 pv; pv.x = lo.x; pv.y = lo.y; pv.z = hi.x; pv.w = hi.y;
      pf[mt] = pv;
    }

#pragma unroll
    for (int kc = 0; kc < 4; ++kc)
#pragma unroll
      for (int dt = 0; dt < 4; ++dt)
        acc[dt] = __builtin_amdgcn_mfma_f32_16x16x16f16(Vf[dt][kc], pf[kc],
                                                        acc[dt], 0, 0, 0);
  };

  for (int kt = 0; kt < 32; kt += 2) {
    body(kt, K0, V0, K1, V1);
    body(kt + 1, K1, V1, K0, V0);
  }

  // l reduction over quads (lanes fr, fr+16, fr+32, fr+48 share a q-col)
  float l = lacc;
  l += __shfl_xor(l, 16);
  l += __shfl_xor(l, 32);
  const float inv = __builtin_amdgcn_rcpf(l);

  __syncthreads();  // done with K/V images before epilogue reuse
  f16* T = smem + (w << 10);  // wave-private [16 q][64 d]
#pragma unroll
  for (int dt = 0; dt < 4; ++dt) {
    f16x4 o = {(f16)(acc[dt][0] * inv), (f16)(acc[dt][1] * inv),
               (f16)(acc[dt][2] * inv), (f16)(acc[dt][3] * inv)};
    *(f16x4*)(T + fr * 64 + dt * 16 + (quad << 2)) = o;
  }
#pragma unroll
  for (int p = 0; p < 2; ++p) {
    const int ql = (p << 3) + (lane >> 3);
    const f16x8 v = *(const f16x8*)(T + ql * 64 + ((lane & 7) << 3));
    *(f16x8*)(Ctx + (qrow0 + ql) * DM + h * HD + ((lane & 7) << 3)) = v;
  }
}

extern "C" void kernel_launch(void* const* d_in, const int* in_sizes, int n_in,
                              void* d_out, int out_size, void* d_ws, size_t ws_size,
                              hipStream_t stream) {
  const float* x  = (const float*)d_in[0];
  const float* Wq = (const float*)d_in[1];
  const float* Wk = (const float*)d_in[2];
  const float* Wv = (const float*)d_in[3];
  const float* Wo = (const float*)d_in[4];

  char* ws = (char*)d_ws;
  f16* xb  = (f16*)(ws);                 // 8 MB; Wb contiguous after it
  f16* Wb  = (f16*)(ws + (8u << 20));    // 4 x 2 MB: Wq,Wk,Wv,Wo
  f16* Wqb = Wb;
  f16* Wkb = Wb + 1048576;
  f16* Wvb = Wb + 2097152;
  f16* Wob = Wb + 3145728;
  f16* Qb  = (f16*)(ws + (16u << 20));   // 8 MB (pre-scaled by log2e/32)
  f16* Kb  = (f16*)(ws + (24u << 20));
  f16* Vtg = (f16*)(ws + (32u << 20));   // frag-layout V, 8 MB
  f16* Ctx = (f16*)(ws + (40u << 20));   // -> 48 MB total

  cast_all<<<8192, 256, 0, stream>>>(x, Wq, Wk, Wv, Wo, xb);

  gemm_qkv<<<dim3(24, 32), 256, 0, stream>>>(xb, Wqb, Wkb, Wvb, Qb, Kb, Vtg);
  attn_mfma<<<dim3(2 * NH * (SEQ / 64)), 256, 0, stream>>>(Qb, Kb, Vtg, Ctx);
  gemm_out<<<dim3(16, 32), 256, 0, stream>>>(Ctx, Wob, (float*)d_out);
}

// Round 5
// 183.645 us; speedup vs baseline: 1.0042x; 1.0042x over previous
//
#include <hip/hip_runtime.h>
#include <cstddef>
#include <cstdint>

#define SEQ 2048
#define DM 1024
#define NH 16
#define HD 64

typedef _Float16 f16;
typedef __attribute__((ext_vector_type(8))) _Float16 f16x8;
typedef __attribute__((ext_vector_type(4))) _Float16 f16x4;
typedef __attribute__((ext_vector_type(2))) _Float16 f16x2;
typedef __attribute__((ext_vector_type(4))) float f32x4;

// one launch: cast x (1M float4) + 4 weights (256K float4 each) into the
// contiguous 16 MB f16 region [xb | Wq | Wk | Wv | Wo]
__global__ __launch_bounds__(256) void cast_all(const float* __restrict__ x,
                                                const float* __restrict__ Wq,
                                                const float* __restrict__ Wk,
                                                const float* __restrict__ Wv,
                                                const float* __restrict__ Wo,
                                                f16* __restrict__ dst) {
  const int i = blockIdx.x * 256 + threadIdx.x;  // float4 index, 2M total
  const float* src;
  int off;
  if (i < 1048576) {
    src = x; off = i;
  } else {
    const int j = i - 1048576;
    const int wsel = j >> 18;
    src = (wsel == 0) ? Wq : (wsel == 1) ? Wk : (wsel == 2) ? Wv : Wo;
    off = j & 262143;
  }
  const float4 v = ((const float4*)src)[off];
  f16x4 o = {(f16)v.x, (f16)v.y, (f16)v.z, (f16)v.w};
  ((f16x4*)dst)[i] = o;
}

__device__ __forceinline__ void gload16(const void* g, void* lds) {
  __builtin_amdgcn_global_load_lds((const __attribute__((address_space(1))) void*)g,
                                   (__attribute__((address_space(3))) void*)lds,
                                   16, 0, 0);
}

// ---------------------------------------------------------------------------
// f16 GEMM mainloop, BK=64 (16 K-steps). LDS tiles XOR-swizzled (T2) via
// pre-swizzled global source (m173); frag reads invert the swizzle.
// ---------------------------------------------------------------------------
__device__ __forceinline__ void gemm_tile(const f16* __restrict__ A,
                                          const f16* __restrict__ B,
                                          f16* As, f16* Bs,
                                          int K, f32x4 acc[4][4]) {
  const int t = threadIdx.x;
  const int lane = t & 63;
  const int w = t >> 6;
  const int wm = (w & 1) << 6, wn = (w >> 1) << 6;
  const int srow = lane >> 3, sg = lane & 7;
  const int fr = lane & 15, q = lane >> 4;
  const int scol = (sg ^ srow) << 3;  // swizzled source col (f16)
  for (int k0 = 0; k0 < K; k0 += 64) {
    __syncthreads();
#pragma unroll
    for (int c = 0; c < 4; ++c) {
      const int row = (w << 5) + (c << 3) + srow;  // row&7 == srow
      gload16(A + (size_t)row * K + k0 + scol, As + (w << 11) + (c << 9));
      gload16(B + (size_t)row * K + k0 + scol, Bs + (w << 11) + (c << 9));
    }
    __syncthreads();
    f16x8 af[4][2], bf[4][2];
#pragma unroll
    for (int i = 0; i < 4; ++i) {
      const int row = wm + (i << 4) + fr;
#pragma unroll
      for (int kh = 0; kh < 2; ++kh)
        af[i][kh] = *(const f16x8*)(As + row * 64 +
                                    ((((kh << 2) | q) ^ (row & 7)) << 3));
    }
#pragma unroll
    for (int j = 0; j < 4; ++j) {
      const int row = wn + (j << 4) + fr;
#pragma unroll
      for (int kh = 0; kh < 2; ++kh)
        bf[j][kh] = *(const f16x8*)(Bs + row * 64 +
                                    ((((kh << 2) | q) ^ (row & 7)) << 3));
    }
#pragma unroll
    for (int kh = 0; kh < 2; ++kh)
#pragma unroll
      for (int i = 0; i < 4; ++i)
#pragma unroll
        for (int j = 0; j < 4; ++j)
          acc[i][j] = __builtin_amdgcn_mfma_f32_16x16x32_f16(af[i][kh], bf[j][kh],
                                                             acc[i][j], 0, 0, 0);
  }
}

// Fused QKV projection. Q pre-scaled by log2(e)/sqrt(d_model).
// V stored in gload_lds-linear frag layout; per 64-key tile kt (4096 f16):
//   flat = bh*131072 + kt*4096 + kc2*2048 + quad*512 + d*8 + par*4 + e
//   holding V[d][key = kc2*32 + par*16 + quad*4 + e]   (d = head dim 0..63)
// Per-lane read of 8 f16 at (kc2, quad, d) gives the exact A-operand of a
// 16x16x32 PV mfma (k-index quad*8+e -> key 32kc2 + 16*(e>=4) + quad*4 + e&3).
#define QSCALE 0.04508422003f /* 1.4426950409/32 */
__global__ __launch_bounds__(256) void gemm_qkv(
    const f16* __restrict__ xb, const f16* __restrict__ Wqb,
    const f16* __restrict__ Wkb, const f16* __restrict__ Wvb,
    f16* __restrict__ Qb, f16* __restrict__ Kb, f16* __restrict__ Vtg) {
  __shared__ f16 smem[16384];
  f16* As = smem;
  f16* Bs = smem + 8192;
  const int which = blockIdx.x >> 3;
  const int bn = (blockIdx.x & 7) << 7;
  const int bm = blockIdx.y << 7;
  const f16* B = (which == 0) ? Wqb : (which == 1) ? Wkb : Wvb;
  f32x4 acc[4][4] = {};
  gemm_tile(xb + (size_t)bm * DM, B + (size_t)bn * DM, As, Bs, DM, acc);
  const int lane = threadIdx.x & 63, w = threadIdx.x >> 6;
  const int wm = (w & 1) << 6, wn = (w >> 1) << 6;
  const int col = lane & 15, q = lane >> 4;
  if (which < 2) {
    f16* C = (which == 0) ? Qb : Kb;
    const float sc = (which == 0) ? QSCALE : 1.0f;
#pragma unroll
    for (int i = 0; i < 4; ++i) {
      const int m = bm + wm + (i << 4) + (q << 2);
#pragma unroll
      for (int j = 0; j < 4; ++j) {
        const int n = bn + wn + (j << 4) + col;
#pragma unroll
        for (int r = 0; r < 4; ++r)
          C[(size_t)(m + r) * DM + n] = (f16)(acc[i][j][r] * sc);
      }
    }
  } else {
    // LDS transpose T[nl][m] (swizzled chunks), then frag-layout global stores.
    __syncthreads();
#pragma unroll
    for (int i = 0; i < 4; ++i) {
      const int m0 = wm + (i << 4) + (q << 2);
      const int cm = m0 >> 3, sub = (m0 >> 2) & 1;
#pragma unroll
      for (int j = 0; j < 4; ++j) {
        const int nl = wn + (j << 4) + col;
        f16x4 o = {(f16)acc[i][j][0], (f16)acc[i][j][1],
                   (f16)acc[i][j][2], (f16)acc[i][j][3]};
        *(f16x4*)(smem + nl * 128 +
                  ((cm ^ (nl & 15) ^ ((nl >> 4) & 3)) << 3) + (sub << 2)) = o;
      }
    }
    __syncthreads();
    const int b = bm >> 11, sb = bm & 2047;
    const int d = threadIdx.x & 63;
    // pair steps (2pr, 2pr+1): s4 and s4+4 share (kt,kc2,quad,d), par 0/1
    // -> one fully-coalesced f16x8 store (lanes d -> contiguous 16B).
#pragma unroll
    for (int pr = 0; pr < 8; ++pr) {
      const int idx0 = (threadIdx.x >> 6) + (pr << 3);  // w + 8*pr
      const int hh = idx0 >> 5;                          // same for both halves
      const int s40 = idx0 & 31;
      const int s41 = s40 + 4;
      const int nl = (hh << 6) + d;
      f16x4 va, vb;
      {
        const int cm = s40 >> 1, sub = s40 & 1;
        va = *(const f16x4*)(smem + nl * 128 +
                             ((cm ^ (nl & 15) ^ ((nl >> 4) & 3)) << 3) + (sub << 2));
      }
      {
        const int cm = s41 >> 1, sub = s41 & 1;
        vb = *(const f16x4*)(smem + nl * 128 +
                             ((cm ^ (nl & 15) ^ ((nl >> 4) & 3)) << 3) + (sub << 2));
      }
      const int bh = (b << 4) + (bn >> 6) + hh;
      const int kt = (sb >> 6) + (s40 >> 4);
      const int kc2 = (s40 & 15) >> 3, qd = s40 & 3;
      const f16x8 vv = __builtin_shufflevector(va, vb, 0, 1, 2, 3, 4, 5, 6, 7);
      const size_t flat = ((size_t)bh << 17) + ((size_t)kt << 12) +
                          ((size_t)kc2 << 11) + ((size_t)qd << 9) + ((size_t)d << 3);
      *(f16x8*)(Vtg + flat) = vv;
    }
  }
}

// Output projection: 128x64 tiles, BK=64, grid (16,32)=512 blocks (2/CU).
__global__ __launch_bounds__(256) void gemm_out(const f16* __restrict__ Ab,
                                                const f16* __restrict__ Wob,
                                                float* __restrict__ out) {
  __shared__ f16 As[128 * 64];
  __shared__ f16 Bs[64 * 64];
  const int bn = blockIdx.x << 6, bm = blockIdx.y << 7;
  const int t = threadIdx.x, lane = t & 63, w = t >> 6;
  const int srow = lane >> 3, sg = lane & 7;
  const int fr = lane & 15, q = lane >> 4;
  const int scol = (sg ^ srow) << 3;
  const f16* A = Ab + (size_t)bm * DM;
  const f16* B = Wob + (size_t)bn * DM;
  const int wm = w << 5;
  f32x4 acc[2][4] = {};
  for (int k0 = 0; k0 < DM; k0 += 64) {
    __syncthreads();
#pragma unroll
    for (int c = 0; c < 4; ++c) {
      const int row = (w << 5) + (c << 3) + srow;
      gload16(A + (size_t)row * DM + k0 + scol, As + (w << 11) + (c << 9));
    }
#pragma unroll
    for (int c = 0; c < 2; ++c) {
      const int row = (w << 4) + (c << 3) + srow;
      gload16(B + (size_t)row * DM + k0 + scol, Bs + (w << 10) + (c << 9));
    }
    __syncthreads();
    f16x8 af[2][2], bf[4][2];
#pragma unroll
    for (int i = 0; i < 2; ++i) {
      const int row = wm + (i << 4) + fr;
#pragma unroll
      for (int kh = 0; kh < 2; ++kh)
        af[i][kh] = *(const f16x8*)(As + row * 64 +
                                    ((((kh << 2) | q) ^ (row & 7)) << 3));
    }
#pragma unroll
    for (int j = 0; j < 4; ++j) {
      const int row = (j << 4) + fr;
#pragma unroll
      for (int kh = 0; kh < 2; ++kh)
        bf[j][kh] = *(const f16x8*)(Bs + row * 64 +
                                    ((((kh << 2) | q) ^ (row & 7)) << 3));
    }
#pragma unroll
    for (int kh = 0; kh < 2; ++kh)
#pragma unroll
      for (int i = 0; i < 2; ++i)
#pragma unroll
        for (int j = 0; j < 4; ++j)
          acc[i][j] = __builtin_amdgcn_mfma_f32_16x16x32_f16(af[i][kh], bf[j][kh],
                                                             acc[i][j], 0, 0, 0);
  }
  const int col = lane & 15;
#pragma unroll
  for (int i = 0; i < 2; ++i) {
    const int m = bm + wm + (i << 4) + (q << 2);
#pragma unroll
    for (int j = 0; j < 4; ++j) {
      const int n = bn + (j << 4) + col;
#pragma unroll
      for (int r = 0; r < 4; ++r)
        out[(size_t)(m + r) * DM + n] = acc[i][j][r];
    }
  }
}

// ---------------------------------------------------------------------------
// MFMA flash attention R13: back to 512 blocks / 2 qt per wave (2x LDS reuse)
//  + PV via 16x16x32 (A = concat(Vf[2kc],Vf[2kc+1]), B = concat(pf4,pf4);
//    k-index (quad*8+e) maps both to key 32kc + 16*(e>=4) + quad*4 + (e&3))
//  + V frags as 8 x ds_read_b128 (new Vtg layout, contiguous per-lane keys)
//  + T15 carry: PV(kt-1) issued after barrier(kt), overlapping stage + ds_reads
//    of tile kt -> MFMA pipe stays fed through the lgkm-wait window.
// ---------------------------------------------------------------------------
__global__ __launch_bounds__(256, 2) void attn_mfma(const f16* __restrict__ Qb,
                                                    const f16* __restrict__ Kb,
                                                    const f16* __restrict__ Vtg,
                                                    f16* __restrict__ Ctx) {
  __shared__ f16 smem[16384];  // 32 KB: K0 | K1 | V0 | V1 (8 KB each)
  const int t = threadIdx.x, lane = t & 63, w = t >> 6;
  const int fr = lane & 15, quad = lane >> 4;
  const int i = blockIdx.x;
  const int j = i >> 3;
  const int bh = ((i & 7) << 2) + (j >> 4);
  const int qt16 = j & 15;
  const int b = bh >> 4, h = bh & 15;

  const size_t qrow0 = (size_t)b * SEQ + qt16 * 128 + w * 32;

  // Q^T B-frags, loop-invariant (2 q-tiles of 16 per wave)
  f16x8 Qf[2][2];
#pragma unroll
  for (int qt = 0; qt < 2; ++qt)
#pragma unroll
    for (int hf = 0; hf < 2; ++hf)
      Qf[qt][hf] = *(const f16x8*)(Qb + (qrow0 + qt * 16 + fr) * DM + h * HD +
                                   hf * 32 + (quad << 3));

  // K gload_lds source: inverse of the cwr swizzle (unchanged, proven)
  const int krow = lane >> 2;
  const int kkc = ((lane & 3) - (lane >> 3)) & 3;
  const f16* Kg = Kb + ((size_t)b * SEQ + 16 * w + krow) * DM + h * HD + (kkc << 3);
  // V gload_lds: linear copy of the 8 KB tile (layout-agnostic)
  const f16* Vg = Vtg + ((size_t)bh << 17) + (((w << 7) + lane) << 3);

  const int crd = ((fr >> 1) << 3) | ((fr & 1) << 2) | (((fr >> 1) + quad) & 3);

  f16* K0 = smem;
  f16* K1 = smem + 4096;
  f16* V0 = smem + 8192;
  f16* V1 = smem + 12288;

  auto stage = [&](int kt, f16* Kimg, f16* Vimg) {
#pragma unroll
    for (int hf = 0; hf < 2; ++hf)
      gload16(Kg + (size_t)kt * 64 * DM + hf * 32, Kimg + (hf << 11) + (w << 9));
#pragma unroll
    for (int c = 0; c < 2; ++c)
      gload16(Vg + kt * 4096 + (c << 9), Vimg + (w << 10) + (c << 9));
  };

  f32x4 acc[2][4] = {};
  float lacc[2] = {0.f, 0.f};
  f16x8 Kf[4][2], Vf[4][2], pf[2][2];

  auto frags = [&](const f16* KR, const f16* VR) {
#pragma unroll
    for (int mt = 0; mt < 4; ++mt)
#pragma unroll
      for (int hf = 0; hf < 2; ++hf)
        Kf[mt][hf] = *(const f16x8*)(KR + (crd << 3) + (hf << 11) + (mt << 9));
#pragma unroll
    for (int dt = 0; dt < 4; ++dt)
#pragma unroll
      for (int kc = 0; kc < 2; ++kc)
        Vf[dt][kc] = *(const f16x8*)(VR + (kc << 11) + (quad << 9) +
                                     (((dt << 4) | fr) << 3));
  };

  auto qkexp = [&]() {
    f32x4 z[2][4] = {};
#pragma unroll
    for (int hf = 0; hf < 2; ++hf)
#pragma unroll
      for (int qt = 0; qt < 2; ++qt)
#pragma unroll
        for (int mt = 0; mt < 4; ++mt)
          z[qt][mt] = __builtin_amdgcn_mfma_f32_16x16x32_f16(Kf[mt][hf], Qf[qt][hf],
                                                             z[qt][mt], 0, 0, 0);
#pragma unroll
    for (int qt = 0; qt < 2; ++qt) {
      f16x4 p4[4];
#pragma unroll
      for (int mt = 0; mt < 4; ++mt) {
        const float p0 = __builtin_amdgcn_exp2f(z[qt][mt][0]);
        const float p1 = __builtin_amdgcn_exp2f(z[qt][mt][1]);
        const float p2 = __builtin_amdgcn_exp2f(z[qt][mt][2]);
        const float p3 = __builtin_amdgcn_exp2f(z[qt][mt][3]);
        lacc[qt] += (p0 + p1) + (p2 + p3);
        const f16x2 lo = __builtin_bit_cast(f16x2, __builtin_amdgcn_cvt_pkrtz(p0, p1));
        const f16x2 hi = __builtin_bit_cast(f16x2, __builtin_amdgcn_cvt_pkrtz(p2, p3));
        f16x4 pv4; pv4.x = lo.x; pv4.y = lo.y; pv4.z = hi.x; pv4.w = hi.y;
        p4[mt] = pv4;
      }
      pf[qt][0] = __builtin_shufflevector(p4[0], p4[1], 0, 1, 2, 3, 4, 5, 6, 7);
      pf[qt][1] = __builtin_shufflevector(p4[2], p4[3], 0, 1, 2, 3, 4, 5, 6, 7);
    }
  };

  auto pv = [&]() {
#pragma unroll
    for (int kc = 0; kc < 2; ++kc)
#pragma unroll
      for (int dt = 0; dt < 4; ++dt)
#pragma unroll
        for (int qt = 0; qt < 2; ++qt)
          acc[qt][dt] = __builtin_amdgcn_mfma_f32_16x16x32_f16(Vf[dt][kc], pf[qt][kc],
                                                               acc[qt][dt], 0, 0, 0);
  };

  stage(0, K0, V0);

  // body 0 (no carried PV)
  __syncthreads();
  stage(1, K1, V1);
  frags(K0, V0);
  qkexp();

  // bodies 1..30; PV of the previous tile issues right after each barrier
  for (int kt = 1; kt < 31; kt += 2) {
    __syncthreads();
    stage(kt + 1, K0, V0);
    pv();             // PV(kt-1), register-only, overlaps stage + ds_reads
    frags(K1, V1);    // tile kt
    qkexp();
    __syncthreads();
    stage(kt + 2, K1, V1);
    pv();             // PV(kt)
    frags(K0, V0);    // tile kt+1
    qkexp();
  }

  // body 31 + final PV
  __syncthreads();
  pv();               // PV(30)
  frags(K1, V1);      // tile 31
  qkexp();
  pv();               // PV(31)

  // l reduction over quads (lanes fr, fr+16, fr+32, fr+48 share a q-col)
  float inv[2];
#pragma unroll
  for (int qt = 0; qt < 2; ++qt) {
    float l = lacc[qt];
    l += __shfl_xor(l, 16);
    l += __shfl_xor(l, 32);
    inv[qt] = __builtin_amdgcn_rcpf(l);
  }

  __syncthreads();  // done with K/V images before epilogue reuse
  f16* T = smem + (w << 11);  // wave-private [32 q][64 d]
#pragma unroll
  for (int qt = 0; qt < 2; ++qt)
#pragma unroll
    for (int dt = 0; dt < 4; ++dt) {
      f16x4 o = {(f16)(acc[qt][dt][0] * inv[qt]), (f16)(acc[qt][dt][1] * inv[qt]),
                 (f16)(acc[qt][dt][2] * inv[qt]), (f16)(acc[qt][dt][3] * inv[qt])};
      *(f16x4*)(T + (qt * 16 + fr) * 64 + dt * 16 + (quad << 2)) = o;
    }
#pragma unroll
  for (int p = 0; p < 4; ++p) {
    const int ql = p * 8 + (lane >> 3);
    const f16x8 v = *(const f16x8*)(T + ql * 64 + ((lane & 7) << 3));
    *(f16x8*)(Ctx + (qrow0 + ql) * DM + h * HD + ((lane & 7) << 3)) = v;
  }
}

extern "C" void kernel_launch(void* const* d_in, const int* in_sizes, int n_in,
                              void* d_out, int out_size, void* d_ws, size_t ws_size,
                              hipStream_t stream) {
  const float* x  = (const float*)d_in[0];
  const float* Wq = (const float*)d_in[1];
  const float* Wk = (const float*)d_in[2];
  const float* Wv = (const float*)d_in[3];
  const float* Wo = (const float*)d_in[4];

  char* ws = (char*)d_ws;
  f16* xb  = (f16*)(ws);                 // 8 MB; Wb contiguous after it
  f16* Wb  = (f16*)(ws + (8u << 20));    // 4 x 2 MB: Wq,Wk,Wv,Wo
  f16* Wqb = Wb;
  f16* Wkb = Wb + 1048576;
  f16* Wvb = Wb + 2097152;
  f16* Wob = Wb + 3145728;
  f16* Qb  = (f16*)(ws + (16u << 20));   // 8 MB (pre-scaled by log2e/32)
  f16* Kb  = (f16*)(ws + (24u << 20));
  f16* Vtg = (f16*)(ws + (32u << 20));   // frag-layout V, 8 MB
  f16* Ctx = (f16*)(ws + (40u << 20));   // -> 48 MB total

  cast_all<<<8192, 256, 0, stream>>>(x, Wq, Wk, Wv, Wo, xb);

  gemm_qkv<<<dim3(24, 32), 256, 0, stream>>>(xb, Wqb, Wkb, Wvb, Qb, Kb, Vtg);
  attn_mfma<<<dim3(2 * NH * (SEQ / 128)), 256, 0, stream>>>(Qb, Kb, Vtg, Ctx);
  gemm_out<<<dim3(16, 32), 256, 0, stream>>>(Ctx, Wob, (float*)d_out);
}

// Round 6
// 182.174 us; speedup vs baseline: 1.0123x; 1.0081x over previous
//
#include <hip/hip_runtime.h>
#include <cstddef>
#include <cstdint>

#define SEQ 2048
#define DM 1024
#define NH 16
#define HD 64

typedef _Float16 f16;
typedef __attribute__((ext_vector_type(8))) _Float16 f16x8;
typedef __attribute__((ext_vector_type(4))) _Float16 f16x4;
typedef __attribute__((ext_vector_type(2))) _Float16 f16x2;
typedef __attribute__((ext_vector_type(4))) float f32x4;

// one launch: cast x (1M float4) + 4 weights (256K float4 each) into the
// contiguous 16 MB f16 region [xb | Wq | Wk | Wv | Wo]
__global__ __launch_bounds__(256) void cast_all(const float* __restrict__ x,
                                                const float* __restrict__ Wq,
                                                const float* __restrict__ Wk,
                                                const float* __restrict__ Wv,
                                                const float* __restrict__ Wo,
                                                f16* __restrict__ dst) {
  const int i = blockIdx.x * 256 + threadIdx.x;  // float4 index, 2M total
  const float* src;
  int off;
  if (i < 1048576) {
    src = x; off = i;
  } else {
    const int j = i - 1048576;
    const int wsel = j >> 18;
    src = (wsel == 0) ? Wq : (wsel == 1) ? Wk : (wsel == 2) ? Wv : Wo;
    off = j & 262143;
  }
  const float4 v = ((const float4*)src)[off];
  f16x4 o = {(f16)v.x, (f16)v.y, (f16)v.z, (f16)v.w};
  ((f16x4*)dst)[i] = o;
}

__device__ __forceinline__ void gload16(const void* g, void* lds) {
  __builtin_amdgcn_global_load_lds((const __attribute__((address_space(1))) void*)g,
                                   (__attribute__((address_space(3))) void*)lds,
                                   16, 0, 0);
}

// ---------------------------------------------------------------------------
// f16 GEMM mainloop, 2-phase double-buffered (T3 minimum recipe), BK=32.
// Per K-step: ONE barrier; stage(next tile -> other buffer) is issued right
// after it and overlaps compute(current buffer). The barrier's implicit
// vmcnt(0) drain lands a full compute phase after the loads were issued, so
// global-load latency is no longer exposed (the old stage->sync->compute
// structure exposed it every step). LDS layout = m97 interleaved
// [chunk8][row16][32], proven conflict-acceptable.
// ---------------------------------------------------------------------------
__device__ __forceinline__ void gemm_tile_db(const f16* __restrict__ A,
                                             const f16* __restrict__ B,
                                             f16* As0, f16* Bs0,
                                             f16* As1, f16* Bs1,
                                             int K, f32x4 acc[4][4]) {
  const int t = threadIdx.x, lane = t & 63, w = t >> 6;
  const int wm = (w & 1) << 6, wn = (w >> 1) << 6;
  const int srow = lane >> 2, scol = (lane & 3) << 3;
  const int fr = lane & 15, q = lane >> 4;
  auto stg = [&](int k0, f16* As, f16* Bs) {
#pragma unroll
    for (int c = 0; c < 2; ++c) {
      const int chunk = (w << 1) + c;
      const int row = (chunk << 4) + srow;
      gload16(A + (size_t)row * K + k0 + scol, As + (chunk << 9));
      gload16(B + (size_t)row * K + k0 + scol, Bs + (chunk << 9));
    }
  };
  auto comp = [&](const f16* As, const f16* Bs) {
    f16x8 af[4], bf[4];
#pragma unroll
    for (int i = 0; i < 4; ++i)
      af[i] = *(const f16x8*)(As + (wm + (i << 4) + fr) * 32 + (q << 3));
#pragma unroll
    for (int j = 0; j < 4; ++j)
      bf[j] = *(const f16x8*)(Bs + (wn + (j << 4) + fr) * 32 + (q << 3));
#pragma unroll
    for (int i = 0; i < 4; ++i)
#pragma unroll
      for (int j = 0; j < 4; ++j)
        acc[i][j] = __builtin_amdgcn_mfma_f32_16x16x32_f16(af[i], bf[j],
                                                           acc[i][j], 0, 0, 0);
  };
  stg(0, As0, Bs0);
  for (int k0 = 0; k0 < K; k0 += 64) {
    __syncthreads();                       // stage(k0) landed; buf1 readers done
    stg(k0 + 32, As1, Bs1);                // k0+32 < K always (K mult of 64)
    comp(As0, Bs0);
    __syncthreads();                       // stage(k0+32) landed; buf0 readers done
    if (k0 + 64 < K) stg(k0 + 64, As0, Bs0);
    comp(As1, Bs1);
  }
}

// Fused QKV projection. Q pre-scaled by log2(e)/sqrt(d_model).
// V stored in gload_lds-linear frag layout; per 64-key tile kt (4096 f16):
//   flat = bh*131072 + kt*4096 + kc2*2048 + quad*512 + d*8 + par*4 + e
//   holding V[d][key = kc2*32 + par*16 + quad*4 + e]   (d = head dim 0..63)
// Per-lane read of 8 f16 at (kc2, quad, d) gives the exact A-operand of a
// 16x16x32 PV mfma (k-index quad*8+e -> key 32kc2 + 16*(e>=4) + quad*4 + e&3).
#define QSCALE 0.04508422003f /* 1.4426950409/32 */
__global__ __launch_bounds__(256) void gemm_qkv(
    const f16* __restrict__ xb, const f16* __restrict__ Wqb,
    const f16* __restrict__ Wkb, const f16* __restrict__ Wvb,
    f16* __restrict__ Qb, f16* __restrict__ Kb, f16* __restrict__ Vtg) {
  __shared__ f16 smem[16384];  // As0|Bs0|As1|Bs1 (4 x 8 KB); reused by V epi
  f16* As0 = smem;
  f16* Bs0 = smem + 4096;
  f16* As1 = smem + 8192;
  f16* Bs1 = smem + 12288;
  const int which = blockIdx.x >> 3;
  const int bn = (blockIdx.x & 7) << 7;
  const int bm = blockIdx.y << 7;
  const f16* B = (which == 0) ? Wqb : (which == 1) ? Wkb : Wvb;
  f32x4 acc[4][4] = {};
  gemm_tile_db(xb + (size_t)bm * DM, B + (size_t)bn * DM, As0, Bs0, As1, Bs1,
               DM, acc);
  const int lane = threadIdx.x & 63, w = threadIdx.x >> 6;
  const int wm = (w & 1) << 6, wn = (w >> 1) << 6;
  const int col = lane & 15, q = lane >> 4;
  if (which < 2) {
    f16* C = (which == 0) ? Qb : Kb;
    const float sc = (which == 0) ? QSCALE : 1.0f;
#pragma unroll
    for (int i = 0; i < 4; ++i) {
      const int m = bm + wm + (i << 4) + (q << 2);
#pragma unroll
      for (int j = 0; j < 4; ++j) {
        const int n = bn + wn + (j << 4) + col;
#pragma unroll
        for (int r = 0; r < 4; ++r)
          C[(size_t)(m + r) * DM + n] = (f16)(acc[i][j][r] * sc);
      }
    }
  } else {
    // LDS transpose T[nl][m] (swizzled chunks), then frag-layout global stores.
    __syncthreads();
#pragma unroll
    for (int i = 0; i < 4; ++i) {
      const int m0 = wm + (i << 4) + (q << 2);
      const int cm = m0 >> 3, sub = (m0 >> 2) & 1;
#pragma unroll
      for (int j = 0; j < 4; ++j) {
        const int nl = wn + (j << 4) + col;
        f16x4 o = {(f16)acc[i][j][0], (f16)acc[i][j][1],
                   (f16)acc[i][j][2], (f16)acc[i][j][3]};
        *(f16x4*)(smem + nl * 128 +
                  ((cm ^ (nl & 15) ^ ((nl >> 4) & 3)) << 3) + (sub << 2)) = o;
      }
    }
    __syncthreads();
    const int b = bm >> 11, sb = bm & 2047;
    const int d = threadIdx.x & 63;
    // pair steps (2pr, 2pr+1): s4 and s4+4 share (kt,kc2,quad,d), par 0/1
    // -> one fully-coalesced f16x8 store (lanes d -> contiguous 16B).
#pragma unroll
    for (int pr = 0; pr < 8; ++pr) {
      const int idx0 = (threadIdx.x >> 6) + (pr << 3);  // w + 8*pr
      const int hh = idx0 >> 5;                          // same for both halves
      const int s40 = idx0 & 31;
      const int s41 = s40 + 4;
      const int nl = (hh << 6) + d;
      f16x4 va, vb;
      {
        const int cm = s40 >> 1, sub = s40 & 1;
        va = *(const f16x4*)(smem + nl * 128 +
                             ((cm ^ (nl & 15) ^ ((nl >> 4) & 3)) << 3) + (sub << 2));
      }
      {
        const int cm = s41 >> 1, sub = s41 & 1;
        vb = *(const f16x4*)(smem + nl * 128 +
                             ((cm ^ (nl & 15) ^ ((nl >> 4) & 3)) << 3) + (sub << 2));
      }
      const int bh = (b << 4) + (bn >> 6) + hh;
      const int kt = (sb >> 6) + (s40 >> 4);
      const int kc2 = (s40 & 15) >> 3, qd = s40 & 3;
      const f16x8 vv = __builtin_shufflevector(va, vb, 0, 1, 2, 3, 4, 5, 6, 7);
      const size_t flat = ((size_t)bh << 17) + ((size_t)kt << 12) +
                          ((size_t)kc2 << 11) + ((size_t)qd << 9) + ((size_t)d << 3);
      *(f16x8*)(Vtg + flat) = vv;
    }
  }
}

// Output projection: 128x64 tiles, BK=32 double-buffered 2-phase,
// grid (16,32)=512 blocks (2/CU). LDS 24 KB.
__global__ __launch_bounds__(256) void gemm_out(const f16* __restrict__ Ab,
                                                const f16* __restrict__ Wob,
                                                float* __restrict__ out) {
  __shared__ f16 smem[12288];  // As0(4K f16)|As1(4K)|Bs0(2K)|Bs1(2K)
  f16* As0 = smem;
  f16* As1 = smem + 4096;
  f16* Bs0 = smem + 8192;
  f16* Bs1 = smem + 10240;
  const int bn = blockIdx.x << 6, bm = blockIdx.y << 7;
  const int t = threadIdx.x, lane = t & 63, w = t >> 6;
  const int srow = lane >> 2, scol = (lane & 3) << 3;
  const int fr = lane & 15, q = lane >> 4;
  const f16* A = Ab + (size_t)bm * DM;
  const f16* B = Wob + (size_t)bn * DM;
  const int wm = w << 5;
  f32x4 acc[2][4] = {};
  auto stg = [&](int k0, f16* As, f16* Bs) {
#pragma unroll
    for (int c = 0; c < 2; ++c) {
      const int chunk = (w << 1) + c;
      const int row = (chunk << 4) + srow;
      gload16(A + (size_t)row * DM + k0 + scol, As + (chunk << 9));
    }
    {
      const int row = (w << 4) + srow;  // chunk = w (64 rows)
      gload16(B + (size_t)row * DM + k0 + scol, Bs + (w << 9));
    }
  };
  auto comp = [&](const f16* As, const f16* Bs) {
    f16x8 af[2], bf[4];
#pragma unroll
    for (int i = 0; i < 2; ++i)
      af[i] = *(const f16x8*)(As + (wm + (i << 4) + fr) * 32 + (q << 3));
#pragma unroll
    for (int j = 0; j < 4; ++j)
      bf[j] = *(const f16x8*)(Bs + ((j << 4) + fr) * 32 + (q << 3));
#pragma unroll
    for (int i = 0; i < 2; ++i)
#pragma unroll
      for (int j = 0; j < 4; ++j)
        acc[i][j] = __builtin_amdgcn_mfma_f32_16x16x32_f16(af[i], bf[j],
                                                           acc[i][j], 0, 0, 0);
  };
  stg(0, As0, Bs0);
  for (int k0 = 0; k0 < DM; k0 += 64) {
    __syncthreads();
    stg(k0 + 32, As1, Bs1);
    comp(As0, Bs0);
    __syncthreads();
    if (k0 + 64 < DM) stg(k0 + 64, As0, Bs0);
    comp(As1, Bs1);
  }
  const int col = lane & 15;
#pragma unroll
  for (int i = 0; i < 2; ++i) {
    const int m = bm + wm + (i << 4) + (q << 2);
#pragma unroll
    for (int j = 0; j < 4; ++j) {
      const int n = bn + (j << 4) + col;
#pragma unroll
      for (int r = 0; r < 4; ++r)
        out[(size_t)(m + r) * DM + n] = acc[i][j][r];
    }
  }
}

// ---------------------------------------------------------------------------
// MFMA flash attention R13 (unchanged): 512 blocks / 2 qt per wave
//  + PV via 16x16x32 (A = concat(Vf[2kc],Vf[2kc+1]), B = concat(pf4,pf4))
//  + V frags as 8 x ds_read_b128 (Vtg layout, contiguous per-lane keys)
//  + T15 carry: PV(kt-1) issued after barrier(kt), overlapping stage + ds_reads
// ---------------------------------------------------------------------------
__global__ __launch_bounds__(256, 2) void attn_mfma(const f16* __restrict__ Qb,
                                                    const f16* __restrict__ Kb,
                                                    const f16* __restrict__ Vtg,
                                                    f16* __restrict__ Ctx) {
  __shared__ f16 smem[16384];  // 32 KB: K0 | K1 | V0 | V1 (8 KB each)
  const int t = threadIdx.x, lane = t & 63, w = t >> 6;
  const int fr = lane & 15, quad = lane >> 4;
  const int i = blockIdx.x;
  const int j = i >> 3;
  const int bh = ((i & 7) << 2) + (j >> 4);
  const int qt16 = j & 15;
  const int b = bh >> 4, h = bh & 15;

  const size_t qrow0 = (size_t)b * SEQ + qt16 * 128 + w * 32;

  // Q^T B-frags, loop-invariant (2 q-tiles of 16 per wave)
  f16x8 Qf[2][2];
#pragma unroll
  for (int qt = 0; qt < 2; ++qt)
#pragma unroll
    for (int hf = 0; hf < 2; ++hf)
      Qf[qt][hf] = *(const f16x8*)(Qb + (qrow0 + qt * 16 + fr) * DM + h * HD +
                                   hf * 32 + (quad << 3));

  // K gload_lds source: inverse of the cwr swizzle (unchanged, proven)
  const int krow = lane >> 2;
  const int kkc = ((lane & 3) - (lane >> 3)) & 3;
  const f16* Kg = Kb + ((size_t)b * SEQ + 16 * w + krow) * DM + h * HD + (kkc << 3);
  // V gload_lds: linear copy of the 8 KB tile (layout-agnostic)
  const f16* Vg = Vtg + ((size_t)bh << 17) + (((w << 7) + lane) << 3);

  const int crd = ((fr >> 1) << 3) | ((fr & 1) << 2) | (((fr >> 1) + quad) & 3);

  f16* K0 = smem;
  f16* K1 = smem + 4096;
  f16* V0 = smem + 8192;
  f16* V1 = smem + 12288;

  auto stage = [&](int kt, f16* Kimg, f16* Vimg) {
#pragma unroll
    for (int hf = 0; hf < 2; ++hf)
      gload16(Kg + (size_t)kt * 64 * DM + hf * 32, Kimg + (hf << 11) + (w << 9));
#pragma unroll
    for (int c = 0; c < 2; ++c)
      gload16(Vg + kt * 4096 + (c << 9), Vimg + (w << 10) + (c << 9));
  };

  f32x4 acc[2][4] = {};
  float lacc[2] = {0.f, 0.f};
  f16x8 Kf[4][2], Vf[4][2], pf[2][2];

  auto frags = [&](const f16* KR, const f16* VR) {
#pragma unroll
    for (int mt = 0; mt < 4; ++mt)
#pragma unroll
      for (int hf = 0; hf < 2; ++hf)
        Kf[mt][hf] = *(const f16x8*)(KR + (crd << 3) + (hf << 11) + (mt << 9));
#pragma unroll
    for (int dt = 0; dt < 4; ++dt)
#pragma unroll
      for (int kc = 0; kc < 2; ++kc)
        Vf[dt][kc] = *(const f16x8*)(VR + (kc << 11) + (quad << 9) +
                                     (((dt << 4) | fr) << 3));
  };

  auto qkexp = [&]() {
    f32x4 z[2][4] = {};
#pragma unroll
    for (int hf = 0; hf < 2; ++hf)
#pragma unroll
      for (int qt = 0; qt < 2; ++qt)
#pragma unroll
        for (int mt = 0; mt < 4; ++mt)
          z[qt][mt] = __builtin_amdgcn_mfma_f32_16x16x32_f16(Kf[mt][hf], Qf[qt][hf],
                                                             z[qt][mt], 0, 0, 0);
#pragma unroll
    for (int qt = 0; qt < 2; ++qt) {
      f16x4 p4[4];
#pragma unroll
      for (int mt = 0; mt < 4; ++mt) {
        const float p0 = __builtin_amdgcn_exp2f(z[qt][mt][0]);
        const float p1 = __builtin_amdgcn_exp2f(z[qt][mt][1]);
        const float p2 = __builtin_amdgcn_exp2f(z[qt][mt][2]);
        const float p3 = __builtin_amdgcn_exp2f(z[qt][mt][3]);
        lacc[qt] += (p0 + p1) + (p2 + p3);
        const f16x2 lo = __builtin_bit_cast(f16x2, __builtin_amdgcn_cvt_pkrtz(p0, p1));
        const f16x2 hi = __builtin_bit_cast(f16x2, __builtin_amdgcn_cvt_pkrtz(p2, p3));
        f16x4 pv4; pv4.x = lo.x; pv4.y = lo.y; pv4.z = hi.x; pv4.w = hi.y;
        p4[mt] = pv4;
      }
      pf[qt][0] = __builtin_shufflevector(p4[0], p4[1], 0, 1, 2, 3, 4, 5, 6, 7);
      pf[qt][1] = __builtin_shufflevector(p4[2], p4[3], 0, 1, 2, 3, 4, 5, 6, 7);
    }
  };

  auto pv = [&]() {
#pragma unroll
    for (int kc = 0; kc < 2; ++kc)
#pragma unroll
      for (int dt = 0; dt < 4; ++dt)
#pragma unroll
        for (int qt = 0; qt < 2; ++qt)
          acc[qt][dt] = __builtin_amdgcn_mfma_f32_16x16x32_f16(Vf[dt][kc], pf[qt][kc],
                                                               acc[qt][dt], 0, 0, 0);
  };

  stage(0, K0, V0);

  // body 0 (no carried PV)
  __syncthreads();
  stage(1, K1, V1);
  frags(K0, V0);
  qkexp();

  // bodies 1..30; PV of the previous tile issues right after each barrier
  for (int kt = 1; kt < 31; kt += 2) {
    __syncthreads();
    stage(kt + 1, K0, V0);
    pv();             // PV(kt-1), register-only, overlaps stage + ds_reads
    frags(K1, V1);    // tile kt
    qkexp();
    __syncthreads();
    stage(kt + 2, K1, V1);
    pv();             // PV(kt)
    frags(K0, V0);    // tile kt+1
    qkexp();
  }

  // body 31 + final PV
  __syncthreads();
  pv();               // PV(30)
  frags(K1, V1);      // tile 31
  qkexp();
  pv();               // PV(31)

  // l reduction over quads (lanes fr, fr+16, fr+32, fr+48 share a q-col)
  float inv[2];
#pragma unroll
  for (int qt = 0; qt < 2; ++qt) {
    float l = lacc[qt];
    l += __shfl_xor(l, 16);
    l += __shfl_xor(l, 32);
    inv[qt] = __builtin_amdgcn_rcpf(l);
  }

  __syncthreads();  // done with K/V images before epilogue reuse
  f16* T = smem + (w << 11);  // wave-private [32 q][64 d]
#pragma unroll
  for (int qt = 0; qt < 2; ++qt)
#pragma unroll
    for (int dt = 0; dt < 4; ++dt) {
      f16x4 o = {(f16)(acc[qt][dt][0] * inv[qt]), (f16)(acc[qt][dt][1] * inv[qt]),
                 (f16)(acc[qt][dt][2] * inv[qt]), (f16)(acc[qt][dt][3] * inv[qt])};
      *(f16x4*)(T + (qt * 16 + fr) * 64 + dt * 16 + (quad << 2)) = o;
    }
#pragma unroll
  for (int p = 0; p < 4; ++p) {
    const int ql = p * 8 + (lane >> 3);
    const f16x8 v = *(const f16x8*)(T + ql * 64 + ((lane & 7) << 3));
    *(f16x8*)(Ctx + (qrow0 + ql) * DM + h * HD + ((lane & 7) << 3)) = v;
  }
}

extern "C" void kernel_launch(void* const* d_in, const int* in_sizes, int n_in,
                              void* d_out, int out_size, void* d_ws, size_t ws_size,
                              hipStream_t stream) {
  const float* x  = (const float*)d_in[0];
  const float* Wq = (const float*)d_in[1];
  const float* Wk = (const float*)d_in[2];
  const float* Wv = (const float*)d_in[3];
  const float* Wo = (const float*)d_in[4];

  char* ws = (char*)d_ws;
  f16* xb  = (f16*)(ws);                 // 8 MB; Wb contiguous after it
  f16* Wb  = (f16*)(ws + (8u << 20));    // 4 x 2 MB: Wq,Wk,Wv,Wo
  f16* Wqb = Wb;
  f16* Wkb = Wb + 1048576;
  f16* Wvb = Wb + 2097152;
  f16* Wob = Wb + 3145728;
  f16* Qb  = (f16*)(ws + (16u << 20));   // 8 MB (pre-scaled by log2e/32)
  f16* Kb  = (f16*)(ws + (24u << 20));
  f16* Vtg = (f16*)(ws + (32u << 20));   // frag-layout V, 8 MB
  f16* Ctx = (f16*)(ws + (40u << 20));   // -> 48 MB total

  cast_all<<<8192, 256, 0, stream>>>(x, Wq, Wk, Wv, Wo, xb);

  gemm_qkv<<<dim3(24, 32), 256, 0, stream>>>(xb, Wqb, Wkb, Wvb, Qb, Kb, Vtg);
  attn_mfma<<<dim3(2 * NH * (SEQ / 128)), 256, 0, stream>>>(Qb, Kb, Vtg, Ctx);
  gemm_out<<<dim3(16, 32), 256, 0, stream>>>(Ctx, Wob, (float*)d_out);
}

// Round 7
// 163.417 us; speedup vs baseline: 1.1285x; 1.1148x over previous
//
#include <hip/hip_runtime.h>
#include <cstddef>
#include <cstdint>

#define SEQ 2048
#define DM 1024
#define NH 16
#define HD 64

typedef _Float16 f16;
typedef __attribute__((ext_vector_type(8))) _Float16 f16x8;
typedef __attribute__((ext_vector_type(4))) _Float16 f16x4;
typedef __attribute__((ext_vector_type(2))) _Float16 f16x2;
typedef __attribute__((ext_vector_type(4))) float f32x4;

// one launch: cast x (1M float4) + 4 weights (256K float4 each) into the
// contiguous 16 MB f16 region [xb | Wq | Wk | Wv | Wo]
__global__ __launch_bounds__(256) void cast_all(const float* __restrict__ x,
                                                const float* __restrict__ Wq,
                                                const float* __restrict__ Wk,
                                                const float* __restrict__ Wv,
                                                const float* __restrict__ Wo,
                                                f16* __restrict__ dst) {
  const int i = blockIdx.x * 256 + threadIdx.x;  // float4 index, 2M total
  const float* src;
  int off;
  if (i < 1048576) {
    src = x; off = i;
  } else {
    const int j = i - 1048576;
    const int wsel = j >> 18;
    src = (wsel == 0) ? Wq : (wsel == 1) ? Wk : (wsel == 2) ? Wv : Wo;
    off = j & 262143;
  }
  const float4 v = ((const float4*)src)[off];
  f16x4 o = {(f16)v.x, (f16)v.y, (f16)v.z, (f16)v.w};
  ((f16x4*)dst)[i] = o;
}

__device__ __forceinline__ void gload16(const void* g, void* lds) {
  __builtin_amdgcn_global_load_lds((const __attribute__((address_space(1))) void*)g,
                                   (__attribute__((address_space(3))) void*)lds,
                                   16, 0, 0);
}

// ---------------------------------------------------------------------------
// f16 GEMM mainloop: BK=64, XOR-swizzled LDS (proven conflict-free: R13
// measured 122K vs 3.27M for the unswizzled m97 layout), 2-phase
// double-buffered. Per K-step: ONE barrier, then stage(next tile -> other
// buffer) overlapping compute(current buffer). gload_lds bumps vmcnt only,
// so compute's ds_reads (lgkm) don't wait on the in-flight stage; the
// stage's vmcnt(0) drain at the NEXT barrier lands a full compute phase
// after issue -> global-load latency hidden AND LDS reads conflict-free.
// Layout: cell (row, cg) holds global colgroup cg ^ (row&7); rows 128B.
// ---------------------------------------------------------------------------
__device__ __forceinline__ void gemm_tile_db(const f16* __restrict__ A,
                                             const f16* __restrict__ B,
                                             f16* As0, f16* Bs0,
                                             f16* As1, f16* Bs1,
                                             int K, f32x4 acc[4][4]) {
  const int t = threadIdx.x, lane = t & 63, w = t >> 6;
  const int wm = (w & 1) << 6, wn = (w >> 1) << 6;
  const int srow = lane >> 3, sg = lane & 7;
  const int fr = lane & 15, q = lane >> 4;
  const int scol = (sg ^ srow) << 3;  // pre-swizzled source col (f16)
  auto stg = [&](int k0, f16* As, f16* Bs) {
#pragma unroll
    for (int c = 0; c < 4; ++c) {
      const int row = (w << 5) + (c << 3) + srow;  // row&7 == srow
      gload16(A + (size_t)row * K + k0 + scol, As + (w << 11) + (c << 9));
      gload16(B + (size_t)row * K + k0 + scol, Bs + (w << 11) + (c << 9));
    }
  };
  auto comp = [&](const f16* As, const f16* Bs) {
    f16x8 af[4][2], bf[4][2];
#pragma unroll
    for (int i = 0; i < 4; ++i) {
      const int row = wm + (i << 4) + fr;
#pragma unroll
      for (int kh = 0; kh < 2; ++kh)
        af[i][kh] = *(const f16x8*)(As + row * 64 +
                                    ((((kh << 2) | q) ^ (row & 7)) << 3));
    }
#pragma unroll
    for (int j = 0; j < 4; ++j) {
      const int row = wn + (j << 4) + fr;
#pragma unroll
      for (int kh = 0; kh < 2; ++kh)
        bf[j][kh] = *(const f16x8*)(Bs + row * 64 +
                                    ((((kh << 2) | q) ^ (row & 7)) << 3));
    }
#pragma unroll
    for (int kh = 0; kh < 2; ++kh)
#pragma unroll
      for (int i = 0; i < 4; ++i)
#pragma unroll
        for (int j = 0; j < 4; ++j)
          acc[i][j] = __builtin_amdgcn_mfma_f32_16x16x32_f16(af[i][kh], bf[j][kh],
                                                             acc[i][j], 0, 0, 0);
  };
  stg(0, As0, Bs0);
  for (int k0 = 0; k0 < K; k0 += 128) {
    __syncthreads();                        // stage(k0) drained; buf1 readers done
    stg(k0 + 64, As1, Bs1);                 // k0+64 < K always (K mult of 128)
    comp(As0, Bs0);
    __syncthreads();                        // stage(k0+64) drained; buf0 readers done
    if (k0 + 128 < K) stg(k0 + 128, As0, Bs0);
    comp(As1, Bs1);
  }
}

// Fused QKV projection. Q pre-scaled by log2(e)/sqrt(d_model).
// V stored in gload_lds-linear frag layout; per 64-key tile kt (4096 f16):
//   flat = bh*131072 + kt*4096 + kc2*2048 + quad*512 + d*8 + par*4 + e
//   holding V[d][key = kc2*32 + par*16 + quad*4 + e]   (d = head dim 0..63)
// Per-lane read of 8 f16 at (kc2, quad, d) gives the exact A-operand of a
// 16x16x32 PV mfma (k-index quad*8+e -> key 32kc2 + 16*(e>=4) + quad*4 + e&3).
#define QSCALE 0.04508422003f /* 1.4426950409/32 */
__global__ __launch_bounds__(256) void gemm_qkv(
    const f16* __restrict__ xb, const f16* __restrict__ Wqb,
    const f16* __restrict__ Wkb, const f16* __restrict__ Wvb,
    f16* __restrict__ Qb, f16* __restrict__ Kb, f16* __restrict__ Vtg) {
  __shared__ f16 smem[32768];  // As0|Bs0|As1|Bs1 (4 x 16 KB); reused by V epi
  f16* As0 = smem;
  f16* Bs0 = smem + 8192;
  f16* As1 = smem + 16384;
  f16* Bs1 = smem + 24576;
  const int which = blockIdx.x >> 3;
  const int bn = (blockIdx.x & 7) << 7;
  const int bm = blockIdx.y << 7;
  const f16* B = (which == 0) ? Wqb : (which == 1) ? Wkb : Wvb;
  f32x4 acc[4][4] = {};
  gemm_tile_db(xb + (size_t)bm * DM, B + (size_t)bn * DM, As0, Bs0, As1, Bs1,
               DM, acc);
  const int lane = threadIdx.x & 63, w = threadIdx.x >> 6;
  const int wm = (w & 1) << 6, wn = (w >> 1) << 6;
  const int col = lane & 15, q = lane >> 4;
  if (which < 2) {
    f16* C = (which == 0) ? Qb : Kb;
    const float sc = (which == 0) ? QSCALE : 1.0f;
#pragma unroll
    for (int i = 0; i < 4; ++i) {
      const int m = bm + wm + (i << 4) + (q << 2);
#pragma unroll
      for (int j = 0; j < 4; ++j) {
        const int n = bn + wn + (j << 4) + col;
#pragma unroll
        for (int r = 0; r < 4; ++r)
          C[(size_t)(m + r) * DM + n] = (f16)(acc[i][j][r] * sc);
      }
    }
  } else {
    // LDS transpose T[nl][m] (swizzled chunks), then frag-layout global stores.
    __syncthreads();
#pragma unroll
    for (int i = 0; i < 4; ++i) {
      const int m0 = wm + (i << 4) + (q << 2);
      const int cm = m0 >> 3, sub = (m0 >> 2) & 1;
#pragma unroll
      for (int j = 0; j < 4; ++j) {
        const int nl = wn + (j << 4) + col;
        f16x4 o = {(f16)acc[i][j][0], (f16)acc[i][j][1],
                   (f16)acc[i][j][2], (f16)acc[i][j][3]};
        *(f16x4*)(smem + nl * 128 +
                  ((cm ^ (nl & 15) ^ ((nl >> 4) & 3)) << 3) + (sub << 2)) = o;
      }
    }
    __syncthreads();
    const int b = bm >> 11, sb = bm & 2047;
    const int d = threadIdx.x & 63;
    // pair steps (2pr, 2pr+1): s4 and s4+4 share (kt,kc2,quad,d), par 0/1
    // -> one fully-coalesced f16x8 store (lanes d -> contiguous 16B).
#pragma unroll
    for (int pr = 0; pr < 8; ++pr) {
      const int idx0 = (threadIdx.x >> 6) + (pr << 3);  // w + 8*pr
      const int hh = idx0 >> 5;                          // same for both halves
      const int s40 = idx0 & 31;
      const int s41 = s40 + 4;
      const int nl = (hh << 6) + d;
      f16x4 va, vb;
      {
        const int cm = s40 >> 1, sub = s40 & 1;
        va = *(const f16x4*)(smem + nl * 128 +
                             ((cm ^ (nl & 15) ^ ((nl >> 4) & 3)) << 3) + (sub << 2));
      }
      {
        const int cm = s41 >> 1, sub = s41 & 1;
        vb = *(const f16x4*)(smem + nl * 128 +
                             ((cm ^ (nl & 15) ^ ((nl >> 4) & 3)) << 3) + (sub << 2));
      }
      const int bh = (b << 4) + (bn >> 6) + hh;
      const int kt = (sb >> 6) + (s40 >> 4);
      const int kc2 = (s40 & 15) >> 3, qd = s40 & 3;
      const f16x8 vv = __builtin_shufflevector(va, vb, 0, 1, 2, 3, 4, 5, 6, 7);
      const size_t flat = ((size_t)bh << 17) + ((size_t)kt << 12) +
                          ((size_t)kc2 << 11) + ((size_t)qd << 9) + ((size_t)d << 3);
      *(f16x8*)(Vtg + flat) = vv;
    }
  }
}

// Output projection: 128x64 tiles, BK=64 double-buffered 2-phase, swizzled
// LDS; grid (16,32)=512 blocks. LDS 48 KB -> 3 blocks/CU.
__global__ __launch_bounds__(256) void gemm_out(const f16* __restrict__ Ab,
                                                const f16* __restrict__ Wob,
                                                float* __restrict__ out) {
  __shared__ f16 smem[24576];  // As0(8K f16)|As1(8K)|Bs0(4K)|Bs1(4K)
  f16* As0 = smem;
  f16* As1 = smem + 8192;
  f16* Bs0 = smem + 16384;
  f16* Bs1 = smem + 20480;
  const int bn = blockIdx.x << 6, bm = blockIdx.y << 7;
  const int t = threadIdx.x, lane = t & 63, w = t >> 6;
  const int srow = lane >> 3, sg = lane & 7;
  const int fr = lane & 15, q = lane >> 4;
  const int scol = (sg ^ srow) << 3;
  const f16* A = Ab + (size_t)bm * DM;
  const f16* B = Wob + (size_t)bn * DM;
  const int wm = w << 5;
  f32x4 acc[2][4] = {};
  auto stg = [&](int k0, f16* As, f16* Bs) {
#pragma unroll
    for (int c = 0; c < 4; ++c) {
      const int row = (w << 5) + (c << 3) + srow;
      gload16(A + (size_t)row * DM + k0 + scol, As + (w << 11) + (c << 9));
    }
#pragma unroll
    for (int c = 0; c < 2; ++c) {
      const int row = (w << 4) + (c << 3) + srow;
      gload16(B + (size_t)row * DM + k0 + scol, Bs + (w << 10) + (c << 9));
    }
  };
  auto comp = [&](const f16* As, const f16* Bs) {
    f16x8 af[2][2], bf[4][2];
#pragma unroll
    for (int i = 0; i < 2; ++i) {
      const int row = wm + (i << 4) + fr;
#pragma unroll
      for (int kh = 0; kh < 2; ++kh)
        af[i][kh] = *(const f16x8*)(As + row * 64 +
                                    ((((kh << 2) | q) ^ (row & 7)) << 3));
    }
#pragma unroll
    for (int j = 0; j < 4; ++j) {
      const int row = (j << 4) + fr;
#pragma unroll
      for (int kh = 0; kh < 2; ++kh)
        bf[j][kh] = *(const f16x8*)(Bs + row * 64 +
                                    ((((kh << 2) | q) ^ (row & 7)) << 3));
    }
#pragma unroll
    for (int kh = 0; kh < 2; ++kh)
#pragma unroll
      for (int i = 0; i < 2; ++i)
#pragma unroll
        for (int j = 0; j < 4; ++j)
          acc[i][j] = __builtin_amdgcn_mfma_f32_16x16x32_f16(af[i][kh], bf[j][kh],
                                                             acc[i][j], 0, 0, 0);
  };
  stg(0, As0, Bs0);
  for (int k0 = 0; k0 < DM; k0 += 128) {
    __syncthreads();
    stg(k0 + 64, As1, Bs1);
    comp(As0, Bs0);
    __syncthreads();
    if (k0 + 128 < DM) stg(k0 + 128, As0, Bs0);
    comp(As1, Bs1);
  }
  const int col = lane & 15;
#pragma unroll
  for (int i = 0; i < 2; ++i) {
    const int m = bm + wm + (i << 4) + (q << 2);
#pragma unroll
    for (int j = 0; j < 4; ++j) {
      const int n = bn + (j << 4) + col;
#pragma unroll
      for (int r = 0; r < 4; ++r)
        out[(size_t)(m + r) * DM + n] = acc[i][j][r];
    }
  }
}

// ---------------------------------------------------------------------------
// MFMA flash attention R13 (unchanged): 512 blocks / 2 qt per wave
//  + PV via 16x16x32 (A = concat(Vf[2kc],Vf[2kc+1]), B = concat(pf4,pf4))
//  + V frags as 8 x ds_read_b128 (Vtg layout, contiguous per-lane keys)
//  + T15 carry: PV(kt-1) issued after barrier(kt), overlapping stage + ds_reads
// ---------------------------------------------------------------------------
__global__ __launch_bounds__(256, 2) void attn_mfma(const f16* __restrict__ Qb,
                                                    const f16* __restrict__ Kb,
                                                    const f16* __restrict__ Vtg,
                                                    f16* __restrict__ Ctx) {
  __shared__ f16 smem[16384];  // 32 KB: K0 | K1 | V0 | V1 (8 KB each)
  const int t = threadIdx.x, lane = t & 63, w = t >> 6;
  const int fr = lane & 15, quad = lane >> 4;
  const int i = blockIdx.x;
  const int j = i >> 3;
  const int bh = ((i & 7) << 2) + (j >> 4);
  const int qt16 = j & 15;
  const int b = bh >> 4, h = bh & 15;

  const size_t qrow0 = (size_t)b * SEQ + qt16 * 128 + w * 32;

  // Q^T B-frags, loop-invariant (2 q-tiles of 16 per wave)
  f16x8 Qf[2][2];
#pragma unroll
  for (int qt = 0; qt < 2; ++qt)
#pragma unroll
    for (int hf = 0; hf < 2; ++hf)
      Qf[qt][hf] = *(const f16x8*)(Qb + (qrow0 + qt * 16 + fr) * DM + h * HD +
                                   hf * 32 + (quad << 3));

  // K gload_lds source: inverse of the cwr swizzle (unchanged, proven)
  const int krow = lane >> 2;
  const int kkc = ((lane & 3) - (lane >> 3)) & 3;
  const f16* Kg = Kb + ((size_t)b * SEQ + 16 * w + krow) * DM + h * HD + (kkc << 3);
  // V gload_lds: linear copy of the 8 KB tile (layout-agnostic)
  const f16* Vg = Vtg + ((size_t)bh << 17) + (((w << 7) + lane) << 3);

  const int crd = ((fr >> 1) << 3) | ((fr & 1) << 2) | (((fr >> 1) + quad) & 3);

  f16* K0 = smem;
  f16* K1 = smem + 4096;
  f16* V0 = smem + 8192;
  f16* V1 = smem + 12288;

  auto stage = [&](int kt, f16* Kimg, f16* Vimg) {
#pragma unroll
    for (int hf = 0; hf < 2; ++hf)
      gload16(Kg + (size_t)kt * 64 * DM + hf * 32, Kimg + (hf << 11) + (w << 9));
#pragma unroll
    for (int c = 0; c < 2; ++c)
      gload16(Vg + kt * 4096 + (c << 9), Vimg + (w << 10) + (c << 9));
  };

  f32x4 acc[2][4] = {};
  float lacc[2] = {0.f, 0.f};
  f16x8 Kf[4][2], Vf[4][2], pf[2][2];

  auto frags = [&](const f16* KR, const f16* VR) {
#pragma unroll
    for (int mt = 0; mt < 4; ++mt)
#pragma unroll
      for (int hf = 0; hf < 2; ++hf)
        Kf[mt][hf] = *(const f16x8*)(KR + (crd << 3) + (hf << 11) + (mt << 9));
#pragma unroll
    for (int dt = 0; dt < 4; ++dt)
#pragma unroll
      for (int kc = 0; kc < 2; ++kc)
        Vf[dt][kc] = *(const f16x8*)(VR + (kc << 11) + (quad << 9) +
                                     (((dt << 4) | fr) << 3));
  };

  auto qkexp = [&]() {
    f32x4 z[2][4] = {};
#pragma unroll
    for (int hf = 0; hf < 2; ++hf)
#pragma unroll
      for (int qt = 0; qt < 2; ++qt)
#pragma unroll
        for (int mt = 0; mt < 4; ++mt)
          z[qt][mt] = __builtin_amdgcn_mfma_f32_16x16x32_f16(Kf[mt][hf], Qf[qt][hf],
                                                             z[qt][mt], 0, 0, 0);
#pragma unroll
    for (int qt = 0; qt < 2; ++qt) {
      f16x4 p4[4];
#pragma unroll
      for (int mt = 0; mt < 4; ++mt) {
        const float p0 = __builtin_amdgcn_exp2f(z[qt][mt][0]);
        const float p1 = __builtin_amdgcn_exp2f(z[qt][mt][1]);
        const float p2 = __builtin_amdgcn_exp2f(z[qt][mt][2]);
        const float p3 = __builtin_amdgcn_exp2f(z[qt][mt][3]);
        lacc[qt] += (p0 + p1) + (p2 + p3);
        const f16x2 lo = __builtin_bit_cast(f16x2, __builtin_amdgcn_cvt_pkrtz(p0, p1));
        const f16x2 hi = __builtin_bit_cast(f16x2, __builtin_amdgcn_cvt_pkrtz(p2, p3));
        f16x4 pv4; pv4.x = lo.x; pv4.y = lo.y; pv4.z = hi.x; pv4.w = hi.y;
        p4[mt] = pv4;
      }
      pf[qt][0] = __builtin_shufflevector(p4[0], p4[1], 0, 1, 2, 3, 4, 5, 6, 7);
      pf[qt][1] = __builtin_shufflevector(p4[2], p4[3], 0, 1, 2, 3, 4, 5, 6, 7);
    }
  };

  auto pv = [&]() {
#pragma unroll
    for (int kc = 0; kc < 2; ++kc)
#pragma unroll
      for (int dt = 0; dt < 4; ++dt)
#pragma unroll
        for (int qt = 0; qt < 2; ++qt)
          acc[qt][dt] = __builtin_amdgcn_mfma_f32_16x16x32_f16(Vf[dt][kc], pf[qt][kc],
                                                               acc[qt][dt], 0, 0, 0);
  };

  stage(0, K0, V0);

  // body 0 (no carried PV)
  __syncthreads();
  stage(1, K1, V1);
  frags(K0, V0);
  qkexp();

  // bodies 1..30; PV of the previous tile issues right after each barrier
  for (int kt = 1; kt < 31; kt += 2) {
    __syncthreads();
    stage(kt + 1, K0, V0);
    pv();             // PV(kt-1), register-only, overlaps stage + ds_reads
    frags(K1, V1);    // tile kt
    qkexp();
    __syncthreads();
    stage(kt + 2, K1, V1);
    pv();             // PV(kt)
    frags(K0, V0);    // tile kt+1
    qkexp();
  }

  // body 31 + final PV
  __syncthreads();
  pv();               // PV(30)
  frags(K1, V1);      // tile 31
  qkexp();
  pv();               // PV(31)

  // l reduction over quads (lanes fr, fr+16, fr+32, fr+48 share a q-col)
  float inv[2];
#pragma unroll
  for (int qt = 0; qt < 2; ++qt) {
    float l = lacc[qt];
    l += __shfl_xor(l, 16);
    l += __shfl_xor(l, 32);
    inv[qt] = __builtin_amdgcn_rcpf(l);
  }

  __syncthreads();  // done with K/V images before epilogue reuse
  f16* T = smem + (w << 11);  // wave-private [32 q][64 d]
#pragma unroll
  for (int qt = 0; qt < 2; ++qt)
#pragma unroll
    for (int dt = 0; dt < 4; ++dt) {
      f16x4 o = {(f16)(acc[qt][dt][0] * inv[qt]), (f16)(acc[qt][dt][1] * inv[qt]),
                 (f16)(acc[qt][dt][2] * inv[qt]), (f16)(acc[qt][dt][3] * inv[qt])};
      *(f16x4*)(T + (qt * 16 + fr) * 64 + dt * 16 + (quad << 2)) = o;
    }
#pragma unroll
  for (int p = 0; p < 4; ++p) {
    const int ql = p * 8 + (lane >> 3);
    const f16x8 v = *(const f16x8*)(T + ql * 64 + ((lane & 7) << 3));
    *(f16x8*)(Ctx + (qrow0 + ql) * DM + h * HD + ((lane & 7) << 3)) = v;
  }
}

extern "C" void kernel_launch(void* const* d_in, const int* in_sizes, int n_in,
                              void* d_out, int out_size, void* d_ws, size_t ws_size,
                              hipStream_t stream) {
  const float* x  = (const float*)d_in[0];
  const float* Wq = (const float*)d_in[1];
  const float* Wk = (const float*)d_in[2];
  const float* Wv = (const float*)d_in[3];
  const float* Wo = (const float*)d_in[4];

  char* ws = (char*)d_ws;
  f16* xb  = (f16*)(ws);                 // 8 MB; Wb contiguous after it
  f16* Wb  = (f16*)(ws + (8u << 20));    // 4 x 2 MB: Wq,Wk,Wv,Wo
  f16* Wqb = Wb;
  f16* Wkb = Wb + 1048576;
  f16* Wvb = Wb + 2097152;
  f16* Wob = Wb + 3145728;
  f16* Qb  = (f16*)(ws + (16u << 20));   // 8 MB (pre-scaled by log2e/32)
  f16* Kb  = (f16*)(ws + (24u << 20));
  f16* Vtg = (f16*)(ws + (32u << 20));   // frag-layout V, 8 MB
  f16* Ctx = (f16*)(ws + (40u << 20));   // -> 48 MB total

  cast_all<<<8192, 256, 0, stream>>>(x, Wq, Wk, Wv, Wo, xb);

  gemm_qkv<<<dim3(24, 32), 256, 0, stream>>>(xb, Wqb, Wkb, Wvb, Qb, Kb, Vtg);
  attn_mfma<<<dim3(2 * NH * (SEQ / 128)), 256, 0, stream>>>(Qb, Kb, Vtg, Ctx);
  gemm_out<<<dim3(16, 32), 256, 0, stream>>>(Ctx, Wob, (float*)d_out);
}